// Round 1
// baseline (9009.199 us; speedup 1.0000x reference)
//
#include <hip/hip_runtime.h>
#include <cmath>

// ConvLSTM: x (8,16,64,64,64) fp32, Wk (256,128,3,3) fp32.
// Per step: conv3x3(z=[x_t || h], Wk) -> i,f,o,g -> c=f*c+i*g, h=o*tanh(c).
// Output: hid (2097152 floats) then cell (2097152 floats) in d_out.

#define BN   8
#define TN   16
#define CIN  64
#define HD   64
#define HH   64
#define WW   64
#define PLANE 4096           // H*W
#define CHW  (HD * PLANE)    // one (64,64,64) volume = 262144 elems
#define TILE 16
#define HCG  8               // hidden channels per block

__global__ __launch_bounds__(256) void convlstm_step(
    const float* __restrict__ x,      // full x (B,T,C,H,W)
    const float* __restrict__ Wk,     // (256,128,3,3)
    const float* __restrict__ hprev,  // (B,HD,H,W) — unused when first
    float* __restrict__ hout,         // (B,HD,H,W)
    float* __restrict__ cbuf,         // (B,HD,H,W) in-place cell state
    int t, int first)
{
    __shared__ float zs[4][18][18];

    const int tx  = threadIdx.x;          // 0..15
    const int ty  = threadIdx.y;          // 0..15
    const int tid = ty * 16 + tx;
    const int tile = blockIdx.x;          // 0..15
    const int ty0 = (tile >> 2) * TILE;
    const int tx0 = (tile & 3) * TILE;
    const int hc0 = blockIdx.y * HCG;     // 0,8,...,56
    const int b   = blockIdx.z;

    const int nIC = first ? CIN : (CIN + HD);

    float acc[HCG][4];
    #pragma unroll
    for (int ol = 0; ol < HCG; ++ol)
        #pragma unroll
        for (int g = 0; g < 4; ++g) acc[ol][g] = 0.f;

    const size_t xbase = ((size_t)b * TN + t) * (size_t)CIN * PLANE;
    const size_t hbase = (size_t)b * CHW;

    for (int ic0 = 0; ic0 < nIC; ic0 += 4) {
        // ---- stage 4 haloed 18x18 planes into LDS ----
        for (int idx = tid; idx < 4 * 324; idx += 256) {
            const int plane = idx / 324;
            const int pos   = idx - plane * 324;
            const int py    = pos / 18;
            const int px    = pos - py * 18;
            const int gy = ty0 + py - 1;
            const int gx = tx0 + px - 1;
            const int ic = ic0 + plane;
            float v = 0.f;
            if (gy >= 0 && gy < HH && gx >= 0 && gx < WW) {
                if (ic < CIN)
                    v = x[xbase + (size_t)ic * PLANE + gy * WW + gx];
                else
                    v = hprev[hbase + (size_t)(ic - CIN) * PLANE + gy * WW + gx];
            }
            zs[plane][py][px] = v;
        }
        __syncthreads();

        #pragma unroll
        for (int icl = 0; icl < 4; ++icl) {
            const int ic = ic0 + icl;
            float zr[9];
            #pragma unroll
            for (int ky = 0; ky < 3; ++ky)
                #pragma unroll
                for (int kx = 0; kx < 3; ++kx)
                    zr[ky * 3 + kx] = zs[icl][ty + ky][tx + kx];

            // weights are wave-uniform -> scalar loads expected
            #pragma unroll
            for (int g = 0; g < 4; ++g) {
                #pragma unroll
                for (int ol = 0; ol < HCG; ++ol) {
                    const int oc = g * HD + hc0 + ol;
                    const float* w = Wk + (size_t)(oc * 128 + ic) * 9;
                    float a = acc[ol][g];
                    #pragma unroll
                    for (int k = 0; k < 9; ++k) a = fmaf(zr[k], w[k], a);
                    acc[ol][g] = a;
                }
            }
        }
        __syncthreads();
    }

    // ---- gates + state update ----
    const int y  = ty0 + ty;
    const int xx = tx0 + tx;
    #pragma unroll
    for (int ol = 0; ol < HCG; ++ol) {
        const size_t off = hbase + (size_t)(hc0 + ol) * PLANE + y * WW + xx;
        const float gi = 1.f / (1.f + __expf(-acc[ol][0]));
        const float gf = 1.f / (1.f + __expf(-acc[ol][1]));
        const float go = 1.f / (1.f + __expf(-acc[ol][2]));
        const float gg = tanhf(acc[ol][3]);
        const float cp = first ? 0.f : cbuf[off];
        const float cn = gf * cp + gi * gg;
        const float hn = go * tanhf(cn);
        cbuf[off] = cn;
        hout[off] = hn;
    }
}

extern "C" void kernel_launch(void* const* d_in, const int* in_sizes, int n_in,
                              void* d_out, int out_size, void* d_ws, size_t ws_size,
                              hipStream_t stream) {
    const float* x  = (const float*)d_in[0];
    const float* Wk = (const float*)d_in[1];
    float* out = (float*)d_out;

    float* hA = (float*)d_ws;                    // 2097152 floats
    float* hB = hA + (size_t)BN * CHW;           // 2097152 floats
    float* cb = out + (size_t)BN * CHW;          // cell lives in d_out[2M:], in-place

    dim3 block(16, 16);
    dim3 grid(16, HD / HCG, BN);

    for (int t = 0; t < TN; ++t) {
        const int first = (t == 0);
        const float* hprev = (t & 1) ? hA : hB;  // t=0: unused
        float* hout = (t == TN - 1) ? out : ((t & 1) ? hB : hA);
        convlstm_step<<<grid, block, 0, stream>>>(x, Wk, hprev, hout, cb, t, first);
    }
}

// Round 2
// 1758.140 us; speedup vs baseline: 5.1243x; 5.1243x over previous
//
#include <hip/hip_runtime.h>
#include <cmath>

// ConvLSTM via bf16 MFMA implicit GEMM.
// x (8,16,64,64,64) fp32, Wk (256,128,3,3) fp32.
// Per step t: conv3x3([x_t || h], Wk) -> i,f,o,g -> c = sig(f)*c + sig(i)*tanh(g),
// h = sig(o)*tanh(c).  d_out = [hid fp32 (2M) | cell fp32 (2M)].
//
// GEMM view per block: M=256 pixels (16x16 spatial tile), N=128 oc
// (one hc-half x 4 gates), K=1152 (4 ic-chunks of 32 x 9 taps).
// Grid = 16 tiles x 2 hc-halves x 8 batch = 256 blocks, 4 waves each.

#define CHW   (64 * 4096)      // one (64,64,64) volume
#define PITCH 40               // LDS z pitch in bf16 (32 used + 8 pad), 80 B = 16B-aligned
#define BUFP  257              // epilogue LDS pitch (floats)

typedef short bf16x8 __attribute__((ext_vector_type(8)));
typedef float f32x4  __attribute__((ext_vector_type(4)));

static __device__ __forceinline__ ushort f2bf(float f) {
    union { float f; unsigned u; } v; v.f = f;
    unsigned u = v.u;
    return (ushort)((u + 0x7FFFu + ((u >> 16) & 1u)) >> 16);
}
static __device__ __forceinline__ float sigf(float x) {
    return 1.f / (1.f + __expf(-x));
}

// One-time weight transform into fragment order:
// Wt[((tap*4+cix)*16+g2)*64 + lane][j] = bf16(Wk[oc=g2*16+(lane&15)][ic=cix*32+(lane>>4)*8+j][ky][kx])
__global__ void transform_w(const float* __restrict__ Wk, ushort* __restrict__ Wt) {
    const int idx  = blockIdx.x * 256 + threadIdx.x;   // 36864 total
    const int lane = idx & 63;
    const int g2   = (idx >> 6) & 15;
    const int cix  = (idx >> 10) & 3;
    const int tap  = idx >> 12;                        // 0..8
    const int oc   = g2 * 16 + (lane & 15);
    const int icb  = cix * 32 + (lane >> 4) * 8;
    const int ky   = tap / 3, kx = tap - ky * 3;
    ushort* dst = Wt + (size_t)idx * 8;
    #pragma unroll
    for (int j = 0; j < 8; ++j) {
        const int ic = icb + j;
        dst[j] = f2bf(Wk[((size_t)(oc * 128 + ic) * 3 + ky) * 3 + kx]);
    }
}

__global__ __launch_bounds__(256, 2) void convlstm_mfma(
    const float*  __restrict__ x,     // (8,16,64,64,64) fp32
    const ushort* __restrict__ Wt,    // fragment-ordered bf16 weights
    const ushort* __restrict__ hin,   // (8,64,64,64) bf16
    ushort*       __restrict__ hout,  // (8,64,64,64) bf16
    float*        __restrict__ cbuf,  // (8,64,64,64) fp32, in-place cell
    float*        __restrict__ hfin,  // (8,64,64,64) fp32 final h (d_out)
    int t, int first, int last)
{
    __shared__ __align__(16) char smem_raw[32 * BUFP * 4];   // 32,896 B
    ushort* zs  = (ushort*)smem_raw;    // [324][PITCH] bf16 (25,920 B)
    float*  buf = (float*)smem_raw;     // [32][BUFP] fp32 epilogue

    const int tid  = threadIdx.x;
    const int lane = tid & 63;
    const int w    = tid >> 6;          // wave 0..3 -> tile rows 4w..4w+3
    const int col  = lane & 15;
    const int quad = lane >> 4;
    const int q8   = quad * 8;

    const int tile = blockIdx.x;
    const int ty0  = (tile >> 2) * 16;
    const int tx0  = (tile & 3) * 16;
    const int by   = blockIdx.y;        // hc half
    const int hc0  = by * 32;
    const int b    = blockIdx.z;

    const float*  xt    = x + ((size_t)b * 16 + t) * CHW;
    const ushort* hin_b = hin + (size_t)b * CHW;
    const size_t  cell0 = (size_t)b * CHW;

    f32x4 acc[4][8];
    #pragma unroll
    for (int r = 0; r < 4; ++r)
        #pragma unroll
        for (int nf = 0; nf < 8; ++nf)
            acc[r][nf] = (f32x4){0.f, 0.f, 0.f, 0.f};

    // ---------------- K loop: 4 ic-chunks x 9 taps ----------------
    for (int cix = 0; cix < 4; ++cix) {
        __syncthreads();   // zs free from previous chunk's reads
        // stage 18x18 haloed tile, 32 channels, transposed [pixel][ic], bf16
        for (int i = tid; i < 2592; i += 256) {          // 8 icq * 324 pix
            const int icq = i / 324;
            const int p   = i - icq * 324;
            const int py  = p / 18;
            const int px  = p - py * 18;
            const int gy  = ty0 + py - 1;
            const int gx  = tx0 + px - 1;
            const bool inb = (gy >= 0) & (gy < 64) & (gx >= 0) & (gx < 64);
            const int gpix = gy * 64 + gx;
            const int icl0 = icq * 4;
            ushort4 v;
            if (cix < 2) {
                const float* src = xt + (size_t)(cix * 32 + icl0) * 4096;
                v.x = inb ? f2bf(src[gpix])          : (ushort)0;
                v.y = inb ? f2bf(src[4096 + gpix])   : (ushort)0;
                v.z = inb ? f2bf(src[8192 + gpix])   : (ushort)0;
                v.w = inb ? f2bf(src[12288 + gpix])  : (ushort)0;
            } else {
                const ushort* src = hin_b + (size_t)((cix - 2) * 32 + icl0) * 4096;
                v.x = inb ? src[gpix]          : (ushort)0;
                v.y = inb ? src[4096 + gpix]   : (ushort)0;
                v.z = inb ? src[8192 + gpix]   : (ushort)0;
                v.w = inb ? src[12288 + gpix]  : (ushort)0;
            }
            *(ushort4*)&zs[p * PITCH + icl0] = v;
        }
        __syncthreads();

        #pragma unroll
        for (int ky = 0; ky < 3; ++ky) {
            #pragma unroll
            for (int kx = 0; kx < 3; ++kx) {
                const int tap = ky * 3 + kx;
                // A fragments: 4 tile rows for this wave
                bf16x8 a[4];
                #pragma unroll
                for (int r = 0; r < 4; ++r) {
                    const int row = 4 * w + r + ky;        // 0..17
                    const int pcol = col + kx;             // 0..17
                    a[r] = *(const bf16x8*)&zs[(row * 18 + pcol) * PITCH + q8];
                }
                // B fragments: 8 oc groups (g in 0..3, f in 0..1)
                const ushort* wb = Wt + (size_t)(tap * 4 + cix) * 16 * 512;
                bf16x8 bfr[8];
                #pragma unroll
                for (int nf = 0; nf < 8; ++nf) {
                    const int g2 = (nf >> 1) * 4 + by * 2 + (nf & 1);
                    bfr[nf] = *(const bf16x8*)(wb + (size_t)g2 * 512 + lane * 8);
                }
                #pragma unroll
                for (int nf = 0; nf < 8; ++nf)
                    #pragma unroll
                    for (int r = 0; r < 4; ++r)
                        acc[r][nf] = __builtin_amdgcn_mfma_f32_16x16x32_bf16(
                            a[r], bfr[nf], acc[r][nf], 0, 0, 0);
            }
        }
    }

    // ---------------- epilogue: gates + state update ----------------
    __syncthreads();   // zs dead; buf live now
    if (!first) {
        // stage cprev coalesced -> LDS
        for (int i = tid; i < 8192; i += 256) {
            const int hc = i >> 8, p = i & 255;
            buf[hc * BUFP + p] =
                cbuf[cell0 + (size_t)(hc0 + hc) * 4096 + (ty0 + (p >> 4)) * 64 + tx0 + (p & 15)];
        }
    }
    __syncthreads();

    // owners: compute cn, hn; stash back into acc slots (cn->acc[r][f], hn->acc[r][2+f])
    #pragma unroll
    for (int r = 0; r < 4; ++r) {
        #pragma unroll
        for (int f = 0; f < 2; ++f) {
            const int hcl = f * 16 + col;
            #pragma unroll
            for (int reg = 0; reg < 4; ++reg) {
                const int p = (4 * w + r) * 16 + quad * 4 + reg;
                const float cc_i = acc[r][0 + f][reg];
                const float cc_f = acc[r][2 + f][reg];
                const float cc_o = acc[r][4 + f][reg];
                const float cc_g = acc[r][6 + f][reg];
                const float cp = first ? 0.f : buf[hcl * BUFP + p];
                const float cn = sigf(cc_f) * cp + sigf(cc_i) * tanhf(cc_g);
                const float hn = sigf(cc_o) * tanhf(cn);
                acc[r][0 + f][reg] = cn;
                acc[r][2 + f][reg] = hn;
            }
        }
    }
    __syncthreads();

    // pass 1: cell -> LDS -> coalesced global store
    #pragma unroll
    for (int r = 0; r < 4; ++r)
        #pragma unroll
        for (int f = 0; f < 2; ++f) {
            const int hcl = f * 16 + col;
            #pragma unroll
            for (int reg = 0; reg < 4; ++reg)
                buf[hcl * BUFP + (4 * w + r) * 16 + quad * 4 + reg] = acc[r][0 + f][reg];
        }
    __syncthreads();
    for (int i = tid; i < 8192; i += 256) {
        const int hc = i >> 8, p = i & 255;
        cbuf[cell0 + (size_t)(hc0 + hc) * 4096 + (ty0 + (p >> 4)) * 64 + tx0 + (p & 15)] =
            buf[hc * BUFP + p];
    }
    __syncthreads();

    // pass 2: hidden -> LDS -> coalesced stores (bf16 ping-pong + fp32 final)
    #pragma unroll
    for (int r = 0; r < 4; ++r)
        #pragma unroll
        for (int f = 0; f < 2; ++f) {
            const int hcl = f * 16 + col;
            #pragma unroll
            for (int reg = 0; reg < 4; ++reg)
                buf[hcl * BUFP + (4 * w + r) * 16 + quad * 4 + reg] = acc[r][2 + f][reg];
        }
    __syncthreads();
    for (int i = tid; i < 8192; i += 256) {
        const int hc = i >> 8, p = i & 255;
        const size_t goff = (size_t)(hc0 + hc) * 4096 + (ty0 + (p >> 4)) * 64 + tx0 + (p & 15);
        const float v = buf[hc * BUFP + p];
        hout[(size_t)b * CHW + goff] = f2bf(v);
        if (last) hfin[(size_t)b * CHW + goff] = v;
    }
}

extern "C" void kernel_launch(void* const* d_in, const int* in_sizes, int n_in,
                              void* d_out, int out_size, void* d_ws, size_t ws_size,
                              hipStream_t stream) {
    const float* x  = (const float*)d_in[0];
    const float* Wk = (const float*)d_in[1];
    float* out = (float*)d_out;

    ushort* Wt  = (ushort*)d_ws;                       // 589,824 B
    ushort* hb0 = (ushort*)((char*)d_ws + 589824);     // 4,194,304 B
    ushort* hb1 = (ushort*)((char*)d_ws + 589824 + 4194304);
    float*  cb  = out + 2097152;                       // cell lives in d_out[2M:]

    hipMemsetAsync(hb0, 0, 4194304, stream);           // h(-1) = 0
    transform_w<<<144, 256, 0, stream>>>(Wk, Wt);

    dim3 grid(16, 2, 8);
    for (int t = 0; t < 16; ++t) {
        const ushort* hin = (t & 1) ? hb1 : hb0;
        ushort* ho        = (t & 1) ? hb0 : hb1;
        convlstm_mfma<<<grid, 256, 0, stream>>>(x, Wt, hin, ho, cb, out,
                                                t, t == 0, t == 15);
    }
}

// Round 3
// 889.595 us; speedup vs baseline: 10.1273x; 1.9763x over previous
//
#include <hip/hip_runtime.h>
#include <cmath>

// ConvLSTM via bf16 MFMA implicit GEMM, round 3.
// Grid 512 blocks (16 tiles x 4 hc-quarters x 8 batch), 256 thr (4 waves),
// 2 blocks/CU. Weights staged in LDS per chunk. States kept NHWC in ws
// (h: bf16, cell: fp32); final kernel transposes to NCHW d_out.

#define CHW 262144                 // 64*64*64 elems per batch volume

typedef short bf16x8 __attribute__((ext_vector_type(8)));
typedef float f32x4  __attribute__((ext_vector_type(4)));

static __device__ __forceinline__ ushort f2bf(float f) {
    union { float f; unsigned u; } v; v.f = f;
    unsigned u = v.u;
    return (ushort)((u + 0x7FFFu + ((u >> 16) & 1u)) >> 16);
}
static __device__ __forceinline__ float bf2f(ushort u) {
    union { unsigned u; float f; } v; v.u = (unsigned)u << 16; return v.f;
}
static __device__ __forceinline__ float sigf(float x) {
    return 1.f / (1.f + __expf(-x));
}

// Wt layout: [cq = cix*4+q][tap][g][lane][8j]  (ushort), 36864*8 total.
// element = bf16(Wk[oc = g*64+q*16+(lane&15)][ic = cix*32+(lane>>4)*8+j][ky][kx])
__global__ void transform_w(const float* __restrict__ Wk, ushort* __restrict__ Wt) {
    const int idx  = blockIdx.x * 256 + threadIdx.x;   // 0..36863
    const int lane = idx & 63;
    const int g    = (idx >> 6) & 3;
    const int r2   = idx >> 8;          // 0..143
    const int tap  = r2 % 9;
    const int cq   = r2 / 9;            // 0..15
    const int q    = cq & 3;
    const int cix  = cq >> 2;
    const int oc   = g * 64 + q * 16 + (lane & 15);
    const int icb  = cix * 32 + (lane >> 4) * 8;
    const int ky   = tap / 3, kx = tap - ky * 3;
    ushort* dst = Wt + (size_t)idx * 8;
    #pragma unroll
    for (int j = 0; j < 8; ++j)
        dst[j] = f2bf(Wk[((size_t)(oc * 128 + icb + j) * 3 + ky) * 3 + kx]);
}

__global__ __launch_bounds__(256, 2) void convlstm_step(
    const float*  __restrict__ x,     // (8,16,64,64,64) fp32 NCHW
    const ushort* __restrict__ Wt,    // fragment-ordered bf16 weights
    const ushort* __restrict__ hin,   // (8,4096,64) bf16 NHWC
    ushort*       __restrict__ hout,  // (8,4096,64) bf16 NHWC
    float*        __restrict__ cell,  // (8,4096,64) fp32 NHWC, in-place
    int t, int first)
{
    __shared__ __align__(16) ushort zs[324 * 40];     // 25,920 B  [pixel][32ic+8pad]
    __shared__ __align__(16) ushort wlds[9 * 4 * 512];// 36,864 B  [tap][g][lane][8]

    const int tid  = threadIdx.x;
    const int lane = tid & 63;
    const int w    = tid >> 6;          // wave 0..3 -> spatial rows 4w..4w+3
    const int col  = lane & 15;
    const int quad = lane >> 4;
    const int q8   = quad * 8;

    const int tile = blockIdx.x;
    const int ty0  = (tile >> 2) * 16;
    const int tx0  = (tile & 3) * 16;
    const int q    = blockIdx.y;        // hc quarter
    const int hc0  = q * 16;
    const int b    = blockIdx.z;

    const float*  xt = x + ((size_t)b * 16 + t) * CHW;
    const ushort* hb = hin + (size_t)b * CHW;
    float*        cb = cell + (size_t)b * CHW;
    ushort*       ho = hout + (size_t)b * CHW;

    const int gy_ = ty0 + 4 * w;        // + r
    const int gx_ = tx0 + quad * 4;     // + reg

    // prefetch previous cell state (acc layout, coalesced 64B segments)
    f32x4 cpv[4];
    #pragma unroll
    for (int r = 0; r < 4; ++r) {
        #pragma unroll
        for (int reg = 0; reg < 4; ++reg) {
            cpv[r][reg] = first ? 0.f
                : cb[((size_t)(gy_ + r) * 64 + gx_ + reg) * 64 + hc0 + col];
        }
    }

    f32x4 acc[4][4];
    #pragma unroll
    for (int r = 0; r < 4; ++r)
        #pragma unroll
        for (int g = 0; g < 4; ++g)
            acc[r][g] = (f32x4){0.f, 0.f, 0.f, 0.f};

    // ---------------- K loop: 4 ic-chunks of 32, 9 taps each ----------------
    for (int cix = 0; cix < 4; ++cix) {
        __syncthreads();   // zs/wlds free from previous chunk's reads

        // stage this chunk's weight slice: 36,864 B contiguous
        {
            const uint4* src = (const uint4*)(Wt + (size_t)(cix * 4 + q) * 18432);
            uint4* dst = (uint4*)wlds;
            #pragma unroll
            for (int k = 0; k < 9; ++k)
                dst[tid + k * 256] = src[tid + k * 256];
        }

        // stage haloed 18x18 z-tile, 32 channels, [pixel][ic] bf16
        if (cix < 2) {
            // x: NCHW fp32, 4 plane loads + cvt per item; item = icq*324 + p
            #pragma unroll
            for (int k = 0; k < 11; ++k) {
                const int i = tid + k * 256;
                if (i < 2592) {
                    const int icq = i / 324;
                    const int p   = i - icq * 324;
                    const int py  = p / 18;
                    const int px  = p - py * 18;
                    const int gy  = ty0 + py - 1;
                    const int gx  = tx0 + px - 1;
                    const bool inb = ((unsigned)gy < 64u) & ((unsigned)gx < 64u);
                    ushort4 v = {0, 0, 0, 0};
                    if (inb) {
                        const float* src = xt + (size_t)(cix * 32 + icq * 4) * 4096
                                              + gy * 64 + gx;
                        v.x = f2bf(src[0]);
                        v.y = f2bf(src[4096]);
                        v.z = f2bf(src[8192]);
                        v.w = f2bf(src[12288]);
                    }
                    *(ushort4*)&zs[p * 40 + icq * 4] = v;
                }
            }
        } else {
            // h: NHWC bf16, one 8B contiguous load per item; item = p*8 + icq
            #pragma unroll
            for (int k = 0; k < 11; ++k) {
                const int i = tid + k * 256;
                if (i < 2592) {
                    const int p   = i >> 3;
                    const int icq = i & 7;
                    const int py  = p / 18;
                    const int px  = p - py * 18;
                    const int gy  = ty0 + py - 1;
                    const int gx  = tx0 + px - 1;
                    const bool inb = ((unsigned)gy < 64u) & ((unsigned)gx < 64u);
                    ushort4 v = {0, 0, 0, 0};
                    if (inb)
                        v = *(const ushort4*)&hb[(size_t)(gy * 64 + gx) * 64
                                                 + (cix - 2) * 32 + icq * 4];
                    *(ushort4*)&zs[p * 40 + icq * 4] = v;
                }
            }
        }
        __syncthreads();

        #pragma unroll
        for (int ky = 0; ky < 3; ++ky) {
            #pragma unroll
            for (int kx = 0; kx < 3; ++kx) {
                const int tap = ky * 3 + kx;
                bf16x8 bfr[4];
                #pragma unroll
                for (int g = 0; g < 4; ++g)
                    bfr[g] = *(const bf16x8*)&wlds[(tap * 4 + g) * 512 + lane * 8];
                bf16x8 av[4];
                #pragma unroll
                for (int r = 0; r < 4; ++r)
                    av[r] = *(const bf16x8*)&zs[((4 * w + r + ky) * 18 + col + kx) * 40 + q8];
                #pragma unroll
                for (int g = 0; g < 4; ++g)
                    #pragma unroll
                    for (int r = 0; r < 4; ++r)
                        acc[r][g] = __builtin_amdgcn_mfma_f32_16x16x32_bf16(
                            av[r], bfr[g], acc[r][g], 0, 0, 0);
            }
        }
    }

    // ---------------- epilogue: gates + state update, direct NHWC stores ----
    #pragma unroll
    for (int r = 0; r < 4; ++r) {
        const size_t rowbase = ((size_t)(gy_ + r) * 64 + gx_) * 64 + hc0 + col;
        #pragma unroll
        for (int reg = 0; reg < 4; ++reg) {
            const float ci = acc[r][0][reg];
            const float cf = acc[r][1][reg];
            const float co = acc[r][2][reg];
            const float cg = acc[r][3][reg];
            const float cn = sigf(cf) * cpv[r][reg] + sigf(ci) * tanhf(cg);
            const float hn = sigf(co) * tanhf(cn);
            cb[rowbase + (size_t)reg * 64] = cn;
            ho[rowbase + (size_t)reg * 64] = f2bf(hn);
        }
    }
}

// NHWC -> NCHW final outputs: d_out = [h fp32 | c fp32], each (8,64,4096)
__global__ __launch_bounds__(256) void conv_out(
    const ushort* __restrict__ hN, const float* __restrict__ cN,
    float* __restrict__ out)
{
    __shared__ float T[64][65];
    const int tid  = threadIdx.x;
    const int pg   = blockIdx.x;        // 64 pixel-groups of 64
    const int b    = blockIdx.y;
    const int tsel = blockIdx.z;        // 0 = h, 1 = c
    const int pix0 = pg * 64;

    #pragma unroll
    for (int k = 0; k < 16; ++k) {
        const int idx = k * 256 + tid;
        const int pl = idx >> 6, ch = idx & 63;
        const size_t src = (size_t)b * CHW + (size_t)(pix0 + pl) * 64 + ch;
        T[pl][ch] = tsel ? cN[src] : bf2f(hN[src]);
    }
    __syncthreads();
    float* base = out + (tsel ? 2097152 : 0);
    #pragma unroll
    for (int k = 0; k < 16; ++k) {
        const int idx = k * 256 + tid;
        const int ch = idx >> 6, pl = idx & 63;
        base[(size_t)b * CHW + (size_t)ch * 4096 + pix0 + pl] = T[pl][ch];
    }
}

extern "C" void kernel_launch(void* const* d_in, const int* in_sizes, int n_in,
                              void* d_out, int out_size, void* d_ws, size_t ws_size,
                              hipStream_t stream) {
    const float* x  = (const float*)d_in[0];
    const float* Wk = (const float*)d_in[1];
    float* out = (float*)d_out;

    ushort* Wt   = (ushort*)d_ws;                                  // 589,824 B
    float*  cellb = (float*)((char*)d_ws + 589824);                // 8,388,608 B
    ushort* hb0  = (ushort*)((char*)d_ws + 589824 + 8388608);      // 4,194,304 B
    ushort* hb1  = hb0 + 2097152;                                  // 4,194,304 B

    hipMemsetAsync(hb0, 0, 4194304, stream);       // h(-1) = 0
    transform_w<<<144, 256, 0, stream>>>(Wk, Wt);

    dim3 grid(16, 4, 8);
    for (int t = 0; t < 16; ++t) {
        const ushort* hi = (t & 1) ? hb1 : hb0;
        ushort*       ho = (t & 1) ? hb0 : hb1;
        convlstm_step<<<grid, 256, 0, stream>>>(x, Wt, hi, ho, cellb, t, t == 0);
    }
    // t=15 wrote hb0
    conv_out<<<dim3(64, 8, 2), 256, 0, stream>>>(hb0, cellb, out);
}